// Round 3
// baseline (752.594 us; speedup 1.0000x reference)
//
#include <hip/hip_runtime.h>
#include <hip/hip_bf16.h>

// B=128, T=512, I=128, H=256, O=1 (fp32 in/out)
// xp = x @ W_ih^T + b_ih + b_hh (stored bf16 in ws)
// h_t = tanh(xp_t + h @ W_hh^T) ; out = sigmoid(h_T @ W_fc^T + b_fc)

#define B_ 128
#define T_ 512
#define I_ 128
#define H_ 256

typedef __attribute__((ext_vector_type(8))) short short8;
typedef __attribute__((ext_vector_type(4))) float floatx4;

__device__ __forceinline__ float tanh_fast(float x) {
    float e = __expf(2.0f * x);
    return 1.0f - 2.0f / (e + 1.0f);
}

__device__ __forceinline__ short f2bf(float f) {
    __hip_bfloat16 h = __float2bfloat16(f);   // RNE
    return *(short*)&h;
}

// ---------------- Kernel W-convert: W_ih fp32 -> bf16 (32768 elems)
__global__ void convert_w_kernel(const float* __restrict__ W, short* __restrict__ Wb) {
    int i = blockIdx.x * 256 + threadIdx.x;
    if (i < H_ * I_) Wb[i] = f2bf(W[i]);
}

// ---------------- Kernel A: xp[m][n] via 16x16x32 bf16 MFMA
// Block = 256 thr = 4 waves. Block tile 64(m) x 256(n).
// Wave w: m-half = w&1 (32 rows = 2 m-tiles), n-half = w>>1 (128 cols = 8 n-tiles).
// W_ih(bf16) fragments fully register-resident (32 frags = 128 VGPR).
// A-operand layout: elem[m = lane&15][k = (lane>>4)*8 + j]; same for B with n.
// C/D layout: col = lane&15, row = (lane>>4)*4 + reg  [verified m89/m91].
__global__ __launch_bounds__(256, 1)
void xp_mfma_kernel(const float* __restrict__ x, const short* __restrict__ Wb,
                    const float* __restrict__ b_ih, const float* __restrict__ b_hh,
                    __hip_bfloat16* __restrict__ xp) {
    const int tid  = threadIdx.x;
    const int wave = tid >> 6, lane = tid & 63;
    const int l15  = lane & 15, quad = lane >> 4;
    const int msub  = wave & 1;
    const int nhalf = wave >> 1;
    const long m0 = (long)blockIdx.x * 64 + msub * 32;
    const int  n0 = nhalf * 128;

    // B-operand (W_ih) fragments: [nt][kq], resident for the whole kernel
    short8 bfrag[8][4];
#pragma unroll
    for (int nt = 0; nt < 8; ++nt)
#pragma unroll
        for (int kq = 0; kq < 4; ++kq)
            bfrag[nt][kq] = *(const short8*)(Wb + (long)(n0 + nt * 16 + l15) * I_ + kq * 32 + quad * 8);

    // A-operand (x) fragments: [mt][kq], fp32 -> bf16 inline
    short8 afrag[2][4];
#pragma unroll
    for (int mt = 0; mt < 2; ++mt)
#pragma unroll
        for (int kq = 0; kq < 4; ++kq) {
            const float* p = x + (m0 + mt * 16 + l15) * I_ + kq * 32 + quad * 8;
            float4 lo = *(const float4*)(p);
            float4 hi = *(const float4*)(p + 4);
            short8 f;
            f[0] = f2bf(lo.x); f[1] = f2bf(lo.y); f[2] = f2bf(lo.z); f[3] = f2bf(lo.w);
            f[4] = f2bf(hi.x); f[5] = f2bf(hi.y); f[6] = f2bf(hi.z); f[7] = f2bf(hi.w);
            afrag[mt][kq] = f;
        }

    floatx4 acc[2][8];
#pragma unroll
    for (int mt = 0; mt < 2; ++mt)
#pragma unroll
        for (int nt = 0; nt < 8; ++nt) acc[mt][nt] = (floatx4){0.f, 0.f, 0.f, 0.f};

#pragma unroll
    for (int kq = 0; kq < 4; ++kq)
#pragma unroll
        for (int mt = 0; mt < 2; ++mt)
#pragma unroll
            for (int nt = 0; nt < 8; ++nt)
                acc[mt][nt] = __builtin_amdgcn_mfma_f32_16x16x32_bf16(
                    afrag[mt][kq], bfrag[nt][kq], acc[mt][nt], 0, 0, 0);

    // epilogue: + bias, bf16 store. value(reg r) -> row quad*4+r, col l15 (+tiles)
    float biasv[8];
#pragma unroll
    for (int nt = 0; nt < 8; ++nt) {
        int n = n0 + nt * 16 + l15;
        biasv[nt] = b_ih[n] + b_hh[n];
    }
#pragma unroll
    for (int mt = 0; mt < 2; ++mt)
#pragma unroll
        for (int nt = 0; nt < 8; ++nt) {
#pragma unroll
            for (int r = 0; r < 4; ++r) {
                long row = m0 + mt * 16 + quad * 4 + r;
                float v = acc[mt][nt][r] + biasv[nt];
                xp[row * H_ + n0 + nt * 16 + l15] = __float2bfloat16(v);
            }
        }
}

// ---------------- Kernel B: per-batch recurrence + fused head
// 512 threads = 128 j-slots (2 hidden units) x 4 k-groups (64 k interleaved quads).
// 128 W_hh floats/thread PINNED in VGPRs via opaque asm (compiler cannot remat).
__global__ __launch_bounds__(512, 2)
void rnn_kernel(const __hip_bfloat162* __restrict__ xp, const float* __restrict__ W_hh,
                const float* __restrict__ W_fc, const float* __restrict__ b_fc,
                float* __restrict__ out) {
    __shared__ float hsh[H_];
    __shared__ float red[8];
    const int tid   = threadIdx.x;
    const int kg    = tid & 3;
    const int jslot = tid >> 2;       // 0..127
    const int j0    = jslot * 2;
    const int b     = blockIdx.x;

    float4 w0[16], w1[16];
    const float* wr = W_hh + (long)j0 * H_;
#pragma unroll
    for (int i = 0; i < 16; ++i) {
        int q = 4 * i + kg;
        w0[i] = *(const float4*)(wr + q * 4);
        w1[i] = *(const float4*)(wr + H_ + q * 4);
    }
    // Pin: make weight values opaque so the compiler cannot sink/remat the loads.
#pragma unroll
    for (int i = 0; i < 16; ++i) {
        asm volatile("" : "+v"(w0[i].x), "+v"(w0[i].y), "+v"(w0[i].z), "+v"(w0[i].w),
                          "+v"(w1[i].x), "+v"(w1[i].y), "+v"(w1[i].z), "+v"(w1[i].w));
    }

    if (tid < H_) hsh[tid] = 0.0f;
    const __hip_bfloat162* xpb = xp + (long)b * T_ * (H_ / 2);
    __syncthreads();

#pragma unroll 1
    for (int t = 0; t < T_; ++t) {
        const __hip_bfloat162 xv = xpb[t * (H_ / 2) + jslot];  // prefetch
        const float4* hq = (const float4*)hsh;
        float acc0 = 0.0f, acc1 = 0.0f;
#pragma unroll
        for (int i = 0; i < 16; ++i) {
            float4 h4 = hq[4 * i + kg];
            acc0 += h4.x * w0[i].x + h4.y * w0[i].y + h4.z * w0[i].z + h4.w * w0[i].w;
            acc1 += h4.x * w1[i].x + h4.y * w1[i].y + h4.z * w1[i].z + h4.w * w1[i].w;
        }
        acc0 += __shfl_xor(acc0, 1); acc0 += __shfl_xor(acc0, 2);
        acc1 += __shfl_xor(acc1, 1); acc1 += __shfl_xor(acc1, 2);
        __syncthreads();
        if (kg == 0) {
            float2 xf = __bfloat1622float2(xv);
            float hn0 = tanh_fast(acc0 + xf.x);
            float hn1 = tanh_fast(acc1 + xf.y);
            ((float2*)hsh)[jslot] = make_float2(hn0, hn1);
        }
        __syncthreads();
    }

    float p = (tid < H_) ? hsh[tid] * W_fc[tid] : 0.0f;
#pragma unroll
    for (int off = 32; off > 0; off >>= 1) p += __shfl_down(p, off);
    if ((tid & 63) == 0) red[tid >> 6] = p;
    __syncthreads();
    if (tid == 0) {
        float tot = b_fc[0];
#pragma unroll
        for (int i = 0; i < 8; ++i) tot += red[i];
        out[b] = 1.0f / (1.0f + __expf(-tot));
    }
}

extern "C" void kernel_launch(void* const* d_in, const int* in_sizes, int n_in,
                              void* d_out, int out_size, void* d_ws, size_t ws_size,
                              hipStream_t stream) {
    const float* x    = (const float*)d_in[0];
    const float* W_ih = (const float*)d_in[1];
    const float* W_hh = (const float*)d_in[2];
    const float* b_ih = (const float*)d_in[3];
    const float* b_hh = (const float*)d_in[4];
    const float* W_fc = (const float*)d_in[5];
    const float* b_fc = (const float*)d_in[6];
    float* out = (float*)d_out;

    // ws layout: xp bf16 [B*T][H] = 33.55 MB, then W_ih bf16 = 64 KB
    __hip_bfloat16* xp = (__hip_bfloat16*)d_ws;
    short* Wb = (short*)((char*)d_ws + (size_t)B_ * T_ * H_ * 2);

    convert_w_kernel<<<(H_ * I_ + 255) / 256, 256, 0, stream>>>(W_ih, Wb);
    xp_mfma_kernel<<<(B_ * T_) / 64, 256, 0, stream>>>(x, Wb, b_ih, b_hh, xp);
    rnn_kernel<<<B_, 512, 0, stream>>>((const __hip_bfloat162*)xp, W_hh, W_fc, b_fc, out);
}

// Round 4
// 674.199 us; speedup vs baseline: 1.1163x; 1.1163x over previous
//
#include <hip/hip_runtime.h>
#include <hip/hip_bf16.h>

// B=128, T=512, I=128, H=256, O=1 (fp32 in/out)
// xp = x @ W_ih^T + b_ih + b_hh  (fp32 in ws, 67.1 MB = proven size)
// h_t = tanh(xp_t + h @ W_hh^T)  via MFMA: D[n][b] = W_hh · h^T  (bf16 in, fp32 acc)
// out = sigmoid(h_T @ W_fc^T + b_fc)

#define B_ 128
#define T_ 512
#define I_ 128
#define H_ 256
#define HP 272   // padded LDS row stride (shorts): breaks bank conflicts

typedef __attribute__((ext_vector_type(8))) short short8;
typedef __attribute__((ext_vector_type(4))) short short4v;
typedef __attribute__((ext_vector_type(4))) float floatx4;

__device__ __forceinline__ float tanh_fast(float x) {
    float e = __expf(2.0f * x);
    return 1.0f - 2.0f / (e + 1.0f);
}
__device__ __forceinline__ short f2bf(float f) {
    __hip_bfloat16 h = __float2bfloat16(f);   // RNE
    return *(short*)&h;
}

// ---------------- Kernel A: xp[m][n] via 16x16x32 bf16 MFMA, fp32 output.
// Block = 256 thr = 4 waves; tile 64(m) x 256(n). W_ih converted fp32->bf16
// inline at load (no convert kernel, no ws slot). Layouts verified round 3.
__global__ __launch_bounds__(256, 1)
void xp_mfma_kernel(const float* __restrict__ x, const float* __restrict__ W_ih,
                    const float* __restrict__ b_ih, const float* __restrict__ b_hh,
                    float* __restrict__ xp) {
    const int tid  = threadIdx.x;
    const int wave = tid >> 6, lane = tid & 63;
    const int l15  = lane & 15, quad = lane >> 4;
    const long m0 = (long)blockIdx.x * 64 + (wave & 1) * 32;
    const int  n0 = (wave >> 1) * 128;

    // B-operand (W_ih) fragments, fp32 loads -> bf16 pack, resident
    short8 bfrag[8][4];
#pragma unroll
    for (int nt = 0; nt < 8; ++nt)
#pragma unroll
        for (int kq = 0; kq < 4; ++kq) {
            const float* p = W_ih + (long)(n0 + nt * 16 + l15) * I_ + kq * 32 + quad * 8;
            float4 lo = *(const float4*)(p);
            float4 hi = *(const float4*)(p + 4);
            short8 f;
            f[0] = f2bf(lo.x); f[1] = f2bf(lo.y); f[2] = f2bf(lo.z); f[3] = f2bf(lo.w);
            f[4] = f2bf(hi.x); f[5] = f2bf(hi.y); f[6] = f2bf(hi.z); f[7] = f2bf(hi.w);
            bfrag[nt][kq] = f;
        }

    // A-operand (x) fragments
    short8 afrag[2][4];
#pragma unroll
    for (int mt = 0; mt < 2; ++mt)
#pragma unroll
        for (int kq = 0; kq < 4; ++kq) {
            const float* p = x + (m0 + mt * 16 + l15) * I_ + kq * 32 + quad * 8;
            float4 lo = *(const float4*)(p);
            float4 hi = *(const float4*)(p + 4);
            short8 f;
            f[0] = f2bf(lo.x); f[1] = f2bf(lo.y); f[2] = f2bf(lo.z); f[3] = f2bf(lo.w);
            f[4] = f2bf(hi.x); f[5] = f2bf(hi.y); f[6] = f2bf(hi.z); f[7] = f2bf(hi.w);
            afrag[mt][kq] = f;
        }

    floatx4 acc[2][8];
#pragma unroll
    for (int mt = 0; mt < 2; ++mt)
#pragma unroll
        for (int nt = 0; nt < 8; ++nt) acc[mt][nt] = (floatx4){0.f, 0.f, 0.f, 0.f};

#pragma unroll
    for (int kq = 0; kq < 4; ++kq)
#pragma unroll
        for (int mt = 0; mt < 2; ++mt)
#pragma unroll
            for (int nt = 0; nt < 8; ++nt)
                acc[mt][nt] = __builtin_amdgcn_mfma_f32_16x16x32_bf16(
                    afrag[mt][kq], bfrag[nt][kq], acc[mt][nt], 0, 0, 0);

    float biasv[8];
#pragma unroll
    for (int nt = 0; nt < 8; ++nt) {
        int n = n0 + nt * 16 + l15;
        biasv[nt] = b_ih[n] + b_hh[n];
    }
#pragma unroll
    for (int mt = 0; mt < 2; ++mt)
#pragma unroll
        for (int nt = 0; nt < 8; ++nt)
#pragma unroll
            for (int r = 0; r < 4; ++r) {
                long row = m0 + mt * 16 + quad * 4 + r;
                xp[row * H_ + n0 + nt * 16 + l15] = acc[mt][nt][r] + biasv[nt];
            }
}

// ---------------- Kernel B: MFMA recurrence, 8 blocks x 16 batches.
// Block = 256 thr = 4 waves; wave owns output cols [wave*64, wave*64+64).
// A-operand = W_hh rows (register-resident: 4 mt x 8 kq x 4 VGPR = 128 VGPR).
// B-operand = h_t from LDS (lane l15 = batch, ds_read_b128).
// D[row=n-in-tile, col=batch] -> tanh -> b64 write of h_{t+1}[batch][4n].
__global__ __launch_bounds__(256, 1)
void rnn_kernel(const float* __restrict__ xp, const float* __restrict__ W_hh,
                const float* __restrict__ W_fc, const float* __restrict__ b_fc,
                float* __restrict__ out) {
    __shared__ __align__(16) short hbuf[2][16][HP];   // h as bf16, padded rows
    const int tid  = threadIdx.x;
    const int wave = tid >> 6, lane = tid & 63;
    const int l15  = lane & 15, quad = lane >> 4;
    const int b0   = blockIdx.x * 16;
    const int n0   = wave * 64;

    // W_hh A-fragments: fp32 load -> bf16, resident across all 512 steps
    short8 wfrag[4][8];
#pragma unroll
    for (int mt = 0; mt < 4; ++mt)
#pragma unroll
        for (int kq = 0; kq < 8; ++kq) {
            const float* p = W_hh + (long)(n0 + mt * 16 + l15) * H_ + kq * 32 + quad * 8;
            float4 lo = *(const float4*)(p);
            float4 hi = *(const float4*)(p + 4);
            short8 f;
            f[0] = f2bf(lo.x); f[1] = f2bf(lo.y); f[2] = f2bf(lo.z); f[3] = f2bf(lo.w);
            f[4] = f2bf(hi.x); f[5] = f2bf(hi.y); f[6] = f2bf(hi.z); f[7] = f2bf(hi.w);
            wfrag[mt][kq] = f;
        }

    // zero both h buffers (h_0 = 0)
    {
        int* hz = (int*)hbuf;
#pragma unroll
        for (int i = tid; i < 2 * 16 * HP / 2; i += 256) hz[i] = 0;
    }
    __syncthreads();

    // xp: lane (l15=batch, quad) reads float4 at col n0 + mt*16 + quad*4
    const float* xpl = xp + (long)(b0 + l15) * T_ * H_ + n0 + quad * 4;
    float4 xv[4], xnext[4];
#pragma unroll
    for (int mt = 0; mt < 4; ++mt) xv[mt] = *(const float4*)(xpl + mt * 16);

    const int laneoff = l15 * HP + quad * 8;   // B-frag read offset within buffer

#pragma unroll 1
    for (int t = 0; t < T_; ++t) {
        // prefetch xp for t+1 (clamped) — consumed next iteration
        const long tn = (t + 1 < T_) ? (t + 1) : (T_ - 1);
#pragma unroll
        for (int mt = 0; mt < 4; ++mt)
            xnext[mt] = *(const float4*)(xpl + tn * H_ + mt * 16);

        // B-fragments: h_t rows from buf[t&1]
        const short* hb = &hbuf[t & 1][0][0];
        short8 hfrag[8];
#pragma unroll
        for (int kq = 0; kq < 8; ++kq)
            hfrag[kq] = *(const short8*)(hb + laneoff + kq * 32);

        floatx4 acc[4];
#pragma unroll
        for (int mt = 0; mt < 4; ++mt) acc[mt] = (floatx4){0.f, 0.f, 0.f, 0.f};
#pragma unroll
        for (int kq = 0; kq < 8; ++kq)
#pragma unroll
            for (int mt = 0; mt < 4; ++mt)
                acc[mt] = __builtin_amdgcn_mfma_f32_16x16x32_bf16(
                    wfrag[mt][kq], hfrag[kq], acc[mt], 0, 0, 0);

        // epilogue: tanh(acc + xp) -> bf16 -> h_{t+1}[batch=l15][n0+mt*16+quad*4 ..+4]
        short* wb = &hbuf[(t + 1) & 1][0][0];
#pragma unroll
        for (int mt = 0; mt < 4; ++mt) {
            short4v hw;
            hw[0] = f2bf(tanh_fast(acc[mt][0] + xv[mt].x));
            hw[1] = f2bf(tanh_fast(acc[mt][1] + xv[mt].y));
            hw[2] = f2bf(tanh_fast(acc[mt][2] + xv[mt].z));
            hw[3] = f2bf(tanh_fast(acc[mt][3] + xv[mt].w));
            *(short4v*)(wb + l15 * HP + n0 + mt * 16 + quad * 4) = hw;
        }
#pragma unroll
        for (int mt = 0; mt < 4; ++mt) xv[mt] = xnext[mt];
        __syncthreads();
    }

    // head: out[b] = sigmoid(b_fc + sum_n h_T[b][n] * W_fc[n]); h_T in buf[0]
    const int bl = tid >> 4, seg = tid & 15;
    const short* hr = &hbuf[0][bl][seg * 16];
    float p = 0.0f;
#pragma unroll
    for (int i = 0; i < 16; ++i) {
        __hip_bfloat16 hv = *(const __hip_bfloat16*)(hr + i);
        p += __bfloat162float(hv) * W_fc[seg * 16 + i];
    }
#pragma unroll
    for (int off = 1; off < 16; off <<= 1) p += __shfl_xor(p, off);
    if (seg == 0) out[b0 + bl] = 1.0f / (1.0f + __expf(-(p + b_fc[0])));
}

extern "C" void kernel_launch(void* const* d_in, const int* in_sizes, int n_in,
                              void* d_out, int out_size, void* d_ws, size_t ws_size,
                              hipStream_t stream) {
    const float* x    = (const float*)d_in[0];
    const float* W_ih = (const float*)d_in[1];
    const float* W_hh = (const float*)d_in[2];
    const float* b_ih = (const float*)d_in[3];
    const float* b_hh = (const float*)d_in[4];
    const float* W_fc = (const float*)d_in[5];
    const float* b_fc = (const float*)d_in[6];
    float* out = (float*)d_out;

    float* xp = (float*)d_ws;   // B*T*H fp32 = 67.1 MB (round-1-proven ws footprint)

    xp_mfma_kernel<<<(B_ * T_) / 64, 256, 0, stream>>>(x, W_ih, b_ih, b_hh, xp);
    rnn_kernel<<<B_ / 16, 256, 0, stream>>>(xp, W_hh, W_fc, b_fc, out);
}